// Round 17
// baseline (449.281 us; speedup 1.0000x reference)
//
#include <hip/hip_runtime.h>
#include <hip/hip_fp8.h>
#include <math.h>

typedef unsigned short u16;
typedef unsigned char u8;
typedef short s16x8 __attribute__((ext_vector_type(8)));
typedef short s16x4 __attribute__((ext_vector_type(4)));
typedef unsigned int u32x4 __attribute__((ext_vector_type(4)));
typedef unsigned int u32x2 __attribute__((ext_vector_type(2)));
typedef __bf16 bf16x8 __attribute__((ext_vector_type(8)));
typedef float f32x4 __attribute__((ext_vector_type(4)));
typedef unsigned short u16x2 __attribute__((ext_vector_type(2)));

__device__ __forceinline__ float bf2f(u16 u) {
  unsigned x = ((unsigned)u) << 16;
  return __builtin_bit_cast(float, x);
}
__device__ __forceinline__ u16 f2bf(float f) {
  unsigned x = __builtin_bit_cast(unsigned, f);
  unsigned r = (x + 0x7FFFu + ((x >> 16) & 1u)) >> 16;
  return (u16)r;
}
__device__ __forceinline__ u8 f2e4(float f) {
  __hip_fp8_e4m3 q(f);
  return (u8)q.__x;
}
// packed f32x2 -> 2 fp8 bytes (hardware v_cvt_pk_fp8_f32 when available)
__device__ __forceinline__ unsigned cvt2e4(float a, float b) {
#if __has_builtin(__builtin_amdgcn_cvt_pk_fp8_f32)
  return (unsigned)__builtin_amdgcn_cvt_pk_fp8_f32(a, b, 0, false) & 0xFFFFu;
#else
  return (unsigned)f2e4(a) | ((unsigned)f2e4(b) << 8);
#endif
}

// ---- bf16 MFMA wrapper (signature-robust) ----
template <typename T>
__device__ __forceinline__ auto mfma_try(T a, T b, f32x4 c, int)
    -> decltype(__builtin_amdgcn_mfma_f32_16x16x32_bf16(a, b, c, 0, 0, 0)) {
  return __builtin_amdgcn_mfma_f32_16x16x32_bf16(a, b, c, 0, 0, 0);
}
template <typename T>
__device__ __forceinline__ f32x4 mfma_try(T a, T b, f32x4 c, long) {
  return __builtin_amdgcn_mfma_f32_16x16x32_bf16(
      __builtin_bit_cast(bf16x8, a), __builtin_bit_cast(bf16x8, b), c, 0, 0, 0);
}
__device__ __forceinline__ f32x4 mfma16x16x32(s16x8 a, s16x8 b, f32x4 c) {
  return mfma_try(a, b, c, 0);
}

// ---- fp8 MFMA: builtin operand type is 'long' (i64) on gfx950 ----
__device__ __forceinline__ f32x4 mfma8(long a, long b, f32x4 c) {
  return __builtin_amdgcn_mfma_f32_16x16x32_fp8_fp8(a, b, c, 0, 0, 0);
}

// ---- async global->LDS, 16B per lane ----
__device__ __forceinline__ void gload_lds16(const u16* g, u16* l) {
  __builtin_amdgcn_global_load_lds(
      (__attribute__((address_space(1))) void*)(u16*)g,
      (__attribute__((address_space(3))) void*)l, 16, 0, 0);
}

// ---------------- K0: pack weights (W1,W2 -> fp8x64 octets; fp_w -> bf16), rowmaps ----
__global__ __launch_bounds__(256) void pack_kernel(
    const float* __restrict__ w1, const float* __restrict__ w2,
    const float* __restrict__ fpw, const int* __restrict__ idx1,
    const int* __restrict__ idx2, u8* __restrict__ w1p8, u8* __restrict__ w2p8,
    u16* __restrict__ fpwp, int* __restrict__ rm1, int* __restrict__ rm2) {
  const int T1 = 589824;           // w1 (384x1536)
  const int T2 = T1 + 589824;      // w2 (1536x384)
  const int T3 = T2 + 147456;      // fp_w (384x384)
  const int T4 = T3 + 50176;       // rowmap1
  const int T5 = T4 + 50176;       // rowmap2
  int stride = gridDim.x * 256;
  for (int i = blockIdx.x * 256 + threadIdx.x; i < T5; i += stride) {
    if (i < T1) {
      int k = i / 1536, n = i - k * 1536;
      w1p8[((size_t)(k >> 3) * 1536 + n) * 8 + (k & 7)] = f2e4(w1[i] * 64.f);
    } else if (i < T2) {
      int t = i - T1;
      int k = t / 384, n = t - k * 384;
      w2p8[((size_t)(k >> 3) * 384 + n) * 8 + (k & 7)] = f2e4(w2[t] * 64.f);
    } else if (i < T3) {
      int t = i - T2;
      int k = t / 384, n = t - k * 384;
      fpwp[((size_t)(k >> 3) * 384 + n) * 8 + (k & 7)] = f2bf(fpw[t]);
    } else if (i < T4) {
      int g = i - T3;
      rm1[g] = (g / 392) * 784 + idx1[g];
    } else {
      int g = i - T4;
      rm2[g] = (g / 392) * 784 + idx2[g];
    }
  }
}

// ---------------- K1: depthwise 7x7 conv + bias -> t (B,N,C) bf16 ----------------
__global__ __launch_bounds__(256) void dwconv_kernel(
    const float* __restrict__ x, const float* __restrict__ dww,
    const float* __restrict__ dwb, u16* __restrict__ t) {
  __shared__ __align__(16) u16 plane[8 * 34 * 40];  // 21760 B
  int tid = threadIdx.x;
  int b = blockIdx.y, c0 = blockIdx.x * 8;
  int ch = tid & 7, row = tid >> 3;
  int c = c0 + ch;

  float wg[49];
#pragma unroll
  for (int k2 = 0; k2 < 49; ++k2) wg[k2] = dww[c * 49 + k2];
  float bias = dwb[c];

  for (int q = tid; q < 1360; q += 256) {
    s16x8 z = {0, 0, 0, 0, 0, 0, 0, 0};
    *(s16x8*)(&plane[q * 8]) = z;
  }
  __syncthreads();
  for (int q = tid; q < 1568; q += 256) {
    int cc = q / 196, seg = q - cc * 196;
    int i = seg / 7, j4 = seg - i * 7;
    const float4 v = *(const float4*)(x + ((size_t)(b * 384 + c0 + cc)) * 784 +
                                      i * 28 + j4 * 4);
    s16x4 p;
    p[0] = (short)f2bf(v.x);
    p[1] = (short)f2bf(v.y);
    p[2] = (short)f2bf(v.z);
    p[3] = (short)f2bf(v.w);
    *(s16x4*)(&plane[cc * 1360 + (3 + i) * 40 + 4 + j4 * 4]) = p;
  }
  __syncthreads();

  if (row < 28) {
    size_t obase = ((size_t)(b * 784 + row * 28)) * 384 + c;
#pragma unroll
    for (int ck = 0; ck < 4; ++ck) {
      float acc[8];
#pragma unroll
      for (int o = 0; o < 8; ++o) acc[o] = bias;
#pragma unroll
      for (int di = 0; di < 7; ++di) {
        const u16* base2 = &plane[ch * 1360 + (row + di) * 40 + ck * 8];
        u32x4 ga = *(const u32x4*)(base2);
        u32x4 gb = *(const u32x4*)(base2 + 8);
        unsigned dw[8] = {ga[0], ga[1], ga[2], ga[3],
                          gb[0], gb[1], gb[2], gb[3]};
        float v[16];
#pragma unroll
        for (int tt = 0; tt < 16; ++tt) {
          unsigned d = dw[tt >> 1];
          v[tt] = (tt & 1) ? __builtin_bit_cast(float, d & 0xFFFF0000u)
                           : __builtin_bit_cast(float, d << 16);
        }
#pragma unroll
        for (int o = 0; o < 8; ++o)
#pragma unroll
          for (int dj = 0; dj < 7; ++dj)
            acc[o] += v[o + dj + 1] * wg[di * 7 + dj];
      }
      int lim = (ck == 3) ? 4 : 8;
#pragma unroll
      for (int o = 0; o < 8; ++o)
        if (o < lim) t[obase + (size_t)(ck * 8 + o) * 384] = f2bf(acc[o]);
    }
  }
}

// ---------------- K2: gather + LayerNorm -> A1 (fp8), A2 (bf16) ----------------
__global__ __launch_bounds__(256) void gatherln_kernel(
    const u16* __restrict__ t, const int* __restrict__ idx1,
    const int* __restrict__ idx2, const float* __restrict__ nw1,
    const float* __restrict__ nb1, const float* __restrict__ nw2,
    const float* __restrict__ nb2, u8* __restrict__ A1f,
    u16* __restrict__ A2) {
  int wid = threadIdx.x >> 6, lane = threadIdx.x & 63;
  int g = blockIdx.x * 4 + wid;
  bool is1 = g < 50176;
  int gg = is1 ? g : g - 50176;
  const int* idx = is1 ? idx1 : idx2;
  int b = gg / 392;
  int jj = gg - b * 392;
  int ntok = idx[b * 392 + jj];
  const u16* src = t + ((size_t)(b * 784 + ntok)) * 384 + lane * 6;
  float v[6];
  u16x2 u0 = *(const u16x2*)(src);
  u16x2 u1 = *(const u16x2*)(src + 2);
  u16x2 u2 = *(const u16x2*)(src + 4);
  v[0] = bf2f(u0[0]); v[1] = bf2f(u0[1]);
  v[2] = bf2f(u1[0]); v[3] = bf2f(u1[1]);
  v[4] = bf2f(u2[0]); v[5] = bf2f(u2[1]);
  float s = 0.f, q = 0.f;
#pragma unroll
  for (int e = 0; e < 6; ++e) { s += v[e]; q += v[e] * v[e]; }
#pragma unroll
  for (int off = 32; off >= 1; off >>= 1) {
    s += __shfl_xor(s, off);
    q += __shfl_xor(q, off);
  }
  float mu = s * (1.f / 384.f);
  float var = q * (1.f / 384.f) - mu * mu;
  float rs = rsqrtf(var + 1e-6f);
  const float* nw = is1 ? nw1 : nw2;
  const float* nb = is1 ? nb1 : nb2;
  int k0 = lane * 6;
  float o[6];
#pragma unroll
  for (int e = 0; e < 6; ++e)
    o[e] = (v[e] - mu) * rs * nw[k0 + e] + nb[k0 + e];
  if (is1) {
    u8* dst = A1f + (size_t)gg * 384 + lane * 6;
#pragma unroll
    for (int e = 0; e < 6; e += 2) *(u16*)(dst + e) = (u16)cvt2e4(o[e], o[e + 1]);
  } else {
    u16* dst = A2 + (size_t)gg * 384 + lane * 6;
#pragma unroll
    for (int e = 0; e < 6; ++e) dst[e] = f2bf(o[e]);
  }
}

// ---------------- K3+K4 FUSED (fp8): U[rm1] = (gelu(A1@W1+b1)@W2 + b2)*gamma ----
// Block 256 thr (4 waves), 64 rows. fp8 e4m3 datapath (W pre-scaled x64).
// SWAPPED operands in both phases: mfma(Wfrag, Afrag) so the D-layout is
// k-local (phase A) / col-local (phase B): P-writes become ONE ds_write_b32
// per tile (was 4 ds_write_b8), U stores become 8B (was 4x 2B), b1/b2/gamma
// loads become float4. Loads/LDS layout/barriers identical to R14.
__global__ __launch_bounds__(256, 2) void fused_mlp_kernel(
    const u8* __restrict__ A, const u8* __restrict__ w1p8,
    const u8* __restrict__ w2p8, const float* __restrict__ b1,
    const float* __restrict__ b2, const float* __restrict__ gamma,
    const int* __restrict__ rm, u16* __restrict__ U) {
  __shared__ __align__(16) u8 Alds[48 * 64 * 8];     // 24576 B
  __shared__ __align__(16) u8 Plds[2][24 * 64 * 8];  // 2 x 12288 B
  int tid = threadIdx.x;
  int wid = tid >> 6, lane = tid & 63;
  int kgl = lane >> 4, rl = lane & 15;
  int cl = lane & 15, rg = (lane >> 4) * 4;
  int m_base = blockIdx.x * 64;

  // stage A-tile (64 rows x 384 fp8 = 24KB): coalesced 16B loads, 2x b64 LDS
  // writes into octet layout [ko][row][8]
#pragma unroll
  for (int it = 0; it < 6; ++it) {
    int c16 = it * 256 + tid;      // 16B chunk id, 24 per row
    int row = c16 / 24, cc = c16 - row * 24;
    u32x4 v = *(const u32x4*)(A + (size_t)(m_base + row) * 384 + cc * 16);
    u32x2 lo = {v[0], v[1]}, hi = {v[2], v[3]};
    *(u32x2*)&Alds[((2 * cc) * 64 + row) * 8] = lo;
    *(u32x2*)&Alds[((2 * cc + 1) * 64 + row) * 8] = hi;
  }

  const f32x4 vzero = {0.f, 0.f, 0.f, 0.f};
  f32x4 accB[4][6];  // [P-row tile i][w2col tile j]
#pragma unroll
  for (int i = 0; i < 4; ++i)
#pragma unroll
    for (int j = 0; j < 6; ++j) accB[i][j] = vzero;

  __syncthreads();

#pragma unroll 1
  for (int c = 0; c < 8; ++c) {
    u8* Pl = Plds[c & 1];
    // ---- phase A (swapped): accA[i][j] holds P[row i*16+cl][w1col jt*16+rg..+3]
    f32x4 accA[4][3];
#pragma unroll
    for (int i = 0; i < 4; ++i)
#pragma unroll
      for (int j = 0; j < 3; ++j) accA[i][j] = vzero;
#pragma unroll
    for (int ks = 0; ks < 12; ++ks) {
      long af[4], bw[3];
#pragma unroll
      for (int i = 0; i < 4; ++i)
        af[i] = *(const long*)&Alds[((ks * 4 + kgl) * 64 + i * 16 + rl) * 8];
#pragma unroll
      for (int j = 0; j < 3; ++j) {
        int col = c * 192 + wid * 48 + j * 16 + rl;
        bw[j] = *(const long*)(w1p8 + ((size_t)(ks * 4 + kgl) * 1536 + col) * 8);
      }
      __builtin_amdgcn_s_setprio(1);
#pragma unroll
      for (int i = 0; i < 4; ++i)
#pragma unroll
        for (int j = 0; j < 3; ++j)
          accA[i][j] = mfma8(bw[j], af[i], accA[i][j]);  // SWAPPED
      __builtin_amdgcn_s_setprio(0);
    }
    // bias + sigmoid-gelu -> Pl fp8: one u32 write per (i,j) tile
#pragma unroll
    for (int j = 0; j < 3; ++j) {
      float4 b4 = *(const float4*)(b1 + c * 192 + wid * 48 + j * 16 + rg);
#pragma unroll
      for (int i = 0; i < 4; ++i) {
        float g0 = accA[i][j][0] * 0.015625f + b4.x;
        float g1 = accA[i][j][1] * 0.015625f + b4.y;
        float g2 = accA[i][j][2] * 0.015625f + b4.z;
        float g3 = accA[i][j][3] * 0.015625f + b4.w;
        g0 = g0 / (1.f + __expf(-1.702f * g0));
        g1 = g1 / (1.f + __expf(-1.702f * g1));
        g2 = g2 / (1.f + __expf(-1.702f * g2));
        g3 = g3 / (1.f + __expf(-1.702f * g3));
        unsigned pk32 = cvt2e4(g0, g1) | (cvt2e4(g2, g3) << 16);
        // local k = wid*48 + j*16 + kgl*4 (+0..3): octet ko2, byte (kgl&1)*4
        int ko2 = wid * 6 + j * 2 + (kgl >> 1);
        *(unsigned*)&Pl[(ko2 * 64 + i * 16 + cl) * 8 + (kgl & 1) * 4] = pk32;
      }
    }
    __syncthreads();
    // ---- phase B (swapped): accB[i][j] holds U[row i*16+cl][w2col jt2*16+rg..+3]
#pragma unroll
    for (int ks = 0; ks < 6; ++ks) {
      long ap[4], bw2[6];
#pragma unroll
      for (int i = 0; i < 4; ++i)
        ap[i] = *(const long*)&Pl[((ks * 4 + kgl) * 64 + i * 16 + rl) * 8];
#pragma unroll
      for (int j = 0; j < 6; ++j) {
        int col = wid * 96 + j * 16 + rl;
        int ko2 = c * 24 + ks * 4 + kgl;
        bw2[j] = *(const long*)(w2p8 + ((size_t)ko2 * 384 + col) * 8);
      }
      __builtin_amdgcn_s_setprio(1);
#pragma unroll
      for (int i = 0; i < 4; ++i)
#pragma unroll
        for (int j = 0; j < 6; ++j)
          accB[i][j] = mfma8(bw2[j], ap[i], accB[i][j]);  // SWAPPED
      __builtin_amdgcn_s_setprio(0);
    }
    // no second barrier: next chunk writes the OTHER P buffer
  }

  // epilogue: thread holds 4 consecutive cols per (i,j) -> 8B stores
#pragma unroll
  for (int i = 0; i < 4; ++i) {
    int m = m_base + i * 16 + cl;
    size_t rowoff = (size_t)rm[m] * 384;
#pragma unroll
    for (int j = 0; j < 6; ++j) {
      int col = wid * 96 + j * 16 + rg;
      float4 b4 = *(const float4*)(b2 + col);
      float4 g4 = *(const float4*)(gamma + col);
      s16x4 o;
      o[0] = (short)f2bf((accB[i][j][0] * 0.015625f + b4.x) * g4.x);
      o[1] = (short)f2bf((accB[i][j][1] * 0.015625f + b4.y) * g4.y);
      o[2] = (short)f2bf((accB[i][j][2] * 0.015625f + b4.z) * g4.z);
      o[3] = (short)f2bf((accB[i][j][3] * 0.015625f + b4.w) * g4.w);
      *(s16x4*)(U + rowoff + col) = o;
    }
  }
}

// ---------------- K5: bf16 MFMA GEMM, 128x128 tile, 4 waves (R5 dbuf) ----
__global__ __launch_bounds__(256) void gemm_kernel(
    const u16* __restrict__ A, const u16* __restrict__ Wp,
    const float* __restrict__ bias, const float* __restrict__ scale,
    const int* __restrict__ rowmap, u16* __restrict__ out, int N, int K,
    int gx) {
  __shared__ __align__(16) u16 As[2][4096];
  __shared__ __align__(16) u16 Bs[2][4096];
  int tid = threadIdx.x;
  int wid = tid >> 6, lane = tid & 63;
  int wm = wid >> 1, wn = wid & 1;
  int nwg = gridDim.x;
  int bid = blockIdx.x;
  int wgid = (bid & 7) * (nwg >> 3) + (bid >> 3);
  int by = wgid / gx, bx = wgid - by * gx;
  int m_base = by * 128, n_base = bx * 128;
  const f32x4 vzero = {0.f, 0.f, 0.f, 0.f};
  f32x4 acc[4][4];
#pragma unroll
  for (int i = 0; i < 4; ++i)
#pragma unroll
    for (int j = 0; j < 4; ++j) acc[i][j] = vzero;
  int nk = K >> 5;

  auto stage = [&](int buf, int kt) {
#pragma unroll
    for (int it = 0; it < 2; ++it) {
      int p = wid * 128 + it * 64 + lane;
      int kg = p >> 7, row = p & 127;
      const u16* ga = A + (size_t)(m_base + row) * K + (kt << 5) + (kg << 3);
      gload_lds16(ga, &As[buf][(wid * 128 + it * 64) * 8]);
    }
#pragma unroll
    for (int it = 0; it < 2; ++it) {
      int p = wid * 128 + it * 64 + lane;
      int kg = p >> 7, col = p & 127;
      const u16* gb = Wp + ((size_t)((kt << 2) + kg) * N + n_base + col) * 8;
      gload_lds16(gb, &Bs[buf][(wid * 128 + it * 64) * 8]);
    }
  };

  stage(0, 0);
  __syncthreads();
  int cur = 0;
  for (int kt = 0; kt < nk; ++kt) {
    if (kt + 1 < nk) stage(cur ^ 1, kt + 1);
    int kg = lane >> 4, r = lane & 15;
    s16x8 af[4], bfr[4];
#pragma unroll
    for (int i = 0; i < 4; ++i)
      af[i] = *(const s16x8*)(&As[cur][(kg * 128 + wm * 64 + i * 16 + r) * 8]);
#pragma unroll
    for (int j = 0; j < 4; ++j)
      bfr[j] = *(const s16x8*)(&Bs[cur][(kg * 128 + wn * 64 + j * 16 + r) * 8]);
#pragma unroll
    for (int i = 0; i < 4; ++i)
#pragma unroll
      for (int j = 0; j < 4; ++j)
        acc[i][j] = mfma16x16x32(af[i], bfr[j], acc[i][j]);
    __syncthreads();
    cur ^= 1;
  }
  int cl = lane & 15;
  int rg = (lane >> 4) * 4;
#pragma unroll
  for (int i = 0; i < 4; ++i) {
#pragma unroll
    for (int reg = 0; reg < 4; ++reg) {
      int m = m_base + wm * 64 + i * 16 + rg + reg;
      size_t rowoff = (size_t)rowmap[m] * 384;
#pragma unroll
      for (int j = 0; j < 4; ++j) {
        int col = n_base + wn * 64 + j * 16 + cl;
        float v = acc[i][j][reg];
        v = (v + bias[col]) * scale[col];
        out[rowoff + col] = f2bf(v);
      }
    }
  }
}

// ---------------- K6: un-transpose (B,N,C)->(B,C,N) + residual add ----------------
// Vectorized: 32c x 128n tile; U reads s16x4 (8B/lane), x/out float4 IO.
__global__ __launch_bounds__(256) void unscatter_add_kernel(
    const u16* __restrict__ U, const float* __restrict__ x,
    float* __restrict__ out) {
  __shared__ float tile[32][129];
  int b = blockIdx.y;
  int ct = blockIdx.x % 12, nt = blockIdx.x / 12;
  int c0 = ct * 32, n0 = nt * 128;
  int tid = threadIdx.x;
#pragma unroll
  for (int it = 0; it < 4; ++it) {
    int q = tid + it * 256;
    int nl = q >> 3, cg = (q & 7) * 4;
    int n = n0 + nl;
    if (n < 784) {
      s16x4 v = *(const s16x4*)(U + ((size_t)(b * 784 + n)) * 384 + c0 + cg);
      tile[cg + 0][nl] = bf2f((u16)v[0]);
      tile[cg + 1][nl] = bf2f((u16)v[1]);
      tile[cg + 2][nl] = bf2f((u16)v[2]);
      tile[cg + 3][nl] = bf2f((u16)v[3]);
    }
  }
  __syncthreads();
#pragma unroll
  for (int it = 0; it < 4; ++it) {
    int q = tid + it * 256;
    int c = q >> 5, nf = (q & 31) * 4;
    int n = n0 + nf;
    if (n + 3 < 784) {
      size_t o = ((size_t)(b * 384 + c0 + c)) * 784 + n;
      float4 xv = *(const float4*)(x + o);
      float4 r;
      r.x = xv.x + tile[c][nf + 0];
      r.y = xv.y + tile[c][nf + 1];
      r.z = xv.z + tile[c][nf + 2];
      r.w = xv.w + tile[c][nf + 3];
      *(float4*)(out + o) = r;
    }
  }
}

extern "C" void kernel_launch(void* const* d_in, const int* in_sizes, int n_in,
                              void* d_out, int out_size, void* d_ws,
                              size_t ws_size, hipStream_t stream) {
  const float* x = (const float*)d_in[0];
  const int* idx1 = (const int*)d_in[1];
  const int* idx2 = (const int*)d_in[2];
  const float* dww = (const float*)d_in[3];
  const float* dwb = (const float*)d_in[4];
  const float* nw = (const float*)d_in[5];
  const float* nb = (const float*)d_in[6];
  const float* w1 = (const float*)d_in[7];
  const float* b1 = (const float*)d_in[8];
  const float* w2 = (const float*)d_in[9];
  const float* b2 = (const float*)d_in[10];
  const float* gamma = (const float*)d_in[11];
  const float* fnw = (const float*)d_in[12];
  const float* fnb = (const float*)d_in[13];
  const float* fpw = (const float*)d_in[14];
  const float* fpb = (const float*)d_in[15];
  const float* fpg = (const float*)d_in[16];

  char* ws = (char*)d_ws;
  u16* t = (u16*)(ws);                     //  77,070,336 B (100352x384 bf16)
  u8* A1f = (u8*)(ws + 77070336);          //  19,267,584 B (50176x384 fp8)
  u16* A2 = (u16*)(ws + 96337920);         //  38,535,168 B (50176x384 bf16)
  u16* U = (u16*)(ws + 134873088);         //  77,070,336 B (100352x384 bf16)
  u8* w1p8 = (u8*)(ws + 211943424);        //     589,824 B
  u8* w2p8 = (u8*)(ws + 212533248);        //     589,824 B
  u16* fpwp = (u16*)(ws + 213123072);      //     294,912 B
  int* rm1 = (int*)(ws + 213417984);       //     200,704 B
  int* rm2 = (int*)(ws + 213618688);       //     200,704 B
  (void)ws_size; (void)in_sizes; (void)n_in; (void)out_size;

  pack_kernel<<<1024, 256, 0, stream>>>(w1, w2, fpw, idx1, idx2, w1p8, w2p8,
                                        fpwp, rm1, rm2);
  dwconv_kernel<<<dim3(48, 128), 256, 0, stream>>>(x, dww, dwb, t);
  gatherln_kernel<<<25088, 256, 0, stream>>>(t, idx1, idx2, nw, nb, fnw, fnb,
                                             A1f, A2);
  fused_mlp_kernel<<<784, 256, 0, stream>>>(A1f, w1p8, w2p8, b1, b2, gamma,
                                            rm1, U);
  gemm_kernel<<<1176, 256, 0, stream>>>(A2, fpwp, fpb, fpg, rm2, U, 384, 384,
                                        3);
  unscatter_add_kernel<<<dim3(84, 128), 256, 0, stream>>>(U, x,
                                                          (float*)d_out);
}

// Round 18
// 420.918 us; speedup vs baseline: 1.0674x; 1.0674x over previous
//
#include <hip/hip_runtime.h>
#include <hip/hip_fp8.h>
#include <math.h>

typedef unsigned short u16;
typedef unsigned char u8;
typedef short s16x8 __attribute__((ext_vector_type(8)));
typedef short s16x4 __attribute__((ext_vector_type(4)));
typedef unsigned int u32x4 __attribute__((ext_vector_type(4)));
typedef unsigned int u32x2 __attribute__((ext_vector_type(2)));
typedef __bf16 bf16x8 __attribute__((ext_vector_type(8)));
typedef float f32x4 __attribute__((ext_vector_type(4)));
typedef unsigned short u16x2 __attribute__((ext_vector_type(2)));

__device__ __forceinline__ float bf2f(u16 u) {
  unsigned x = ((unsigned)u) << 16;
  return __builtin_bit_cast(float, x);
}
__device__ __forceinline__ u16 f2bf(float f) {
  unsigned x = __builtin_bit_cast(unsigned, f);
  unsigned r = (x + 0x7FFFu + ((x >> 16) & 1u)) >> 16;
  return (u16)r;
}
__device__ __forceinline__ u8 f2e4(float f) {
  __hip_fp8_e4m3 q(f);
  return (u8)q.__x;
}
// packed f32x2 -> 2 fp8 bytes (hardware v_cvt_pk_fp8_f32 when available)
__device__ __forceinline__ unsigned cvt2e4(float a, float b) {
#if __has_builtin(__builtin_amdgcn_cvt_pk_fp8_f32)
  return (unsigned)__builtin_amdgcn_cvt_pk_fp8_f32(a, b, 0, false) & 0xFFFFu;
#else
  return (unsigned)f2e4(a) | ((unsigned)f2e4(b) << 8);
#endif
}

// ---- bf16 MFMA wrapper (signature-robust) ----
template <typename T>
__device__ __forceinline__ auto mfma_try(T a, T b, f32x4 c, int)
    -> decltype(__builtin_amdgcn_mfma_f32_16x16x32_bf16(a, b, c, 0, 0, 0)) {
  return __builtin_amdgcn_mfma_f32_16x16x32_bf16(a, b, c, 0, 0, 0);
}
template <typename T>
__device__ __forceinline__ f32x4 mfma_try(T a, T b, f32x4 c, long) {
  return __builtin_amdgcn_mfma_f32_16x16x32_bf16(
      __builtin_bit_cast(bf16x8, a), __builtin_bit_cast(bf16x8, b), c, 0, 0, 0);
}
__device__ __forceinline__ f32x4 mfma16x16x32(s16x8 a, s16x8 b, f32x4 c) {
  return mfma_try(a, b, c, 0);
}

// ---- fp8 MFMA: builtin operand type is 'long' (i64) on gfx950 ----
__device__ __forceinline__ f32x4 mfma8(long a, long b, f32x4 c) {
  return __builtin_amdgcn_mfma_f32_16x16x32_fp8_fp8(a, b, c, 0, 0, 0);
}

// ---- async global->LDS, 16B per lane ----
__device__ __forceinline__ void gload_lds16(const u16* g, u16* l) {
  __builtin_amdgcn_global_load_lds(
      (__attribute__((address_space(1))) void*)(u16*)g,
      (__attribute__((address_space(3))) void*)l, 16, 0, 0);
}

// ---------------- K0: pack weights (W1,W2 -> fp8x64 octets; fp_w -> bf16), rowmaps ----
__global__ __launch_bounds__(256) void pack_kernel(
    const float* __restrict__ w1, const float* __restrict__ w2,
    const float* __restrict__ fpw, const int* __restrict__ idx1,
    const int* __restrict__ idx2, u8* __restrict__ w1p8, u8* __restrict__ w2p8,
    u16* __restrict__ fpwp, int* __restrict__ rm1, int* __restrict__ rm2) {
  const int T1 = 589824;           // w1 (384x1536)
  const int T2 = T1 + 589824;      // w2 (1536x384)
  const int T3 = T2 + 147456;      // fp_w (384x384)
  const int T4 = T3 + 50176;       // rowmap1
  const int T5 = T4 + 50176;       // rowmap2
  int stride = gridDim.x * 256;
  for (int i = blockIdx.x * 256 + threadIdx.x; i < T5; i += stride) {
    if (i < T1) {
      int k = i / 1536, n = i - k * 1536;
      w1p8[((size_t)(k >> 3) * 1536 + n) * 8 + (k & 7)] = f2e4(w1[i] * 64.f);
    } else if (i < T2) {
      int t = i - T1;
      int k = t / 384, n = t - k * 384;
      w2p8[((size_t)(k >> 3) * 384 + n) * 8 + (k & 7)] = f2e4(w2[t] * 64.f);
    } else if (i < T3) {
      int t = i - T2;
      int k = t / 384, n = t - k * 384;
      fpwp[((size_t)(k >> 3) * 384 + n) * 8 + (k & 7)] = f2bf(fpw[t]);
    } else if (i < T4) {
      int g = i - T3;
      rm1[g] = (g / 392) * 784 + idx1[g];
    } else {
      int g = i - T4;
      rm2[g] = (g / 392) * 784 + idx2[g];
    }
  }
}

// ---------------- K1: depthwise 7x7 conv + bias -> t (B,N,C) bf16 ----------------
__global__ __launch_bounds__(256) void dwconv_kernel(
    const float* __restrict__ x, const float* __restrict__ dww,
    const float* __restrict__ dwb, u16* __restrict__ t) {
  __shared__ __align__(16) u16 plane[8 * 34 * 40];  // 21760 B
  int tid = threadIdx.x;
  int b = blockIdx.y, c0 = blockIdx.x * 8;
  int ch = tid & 7, row = tid >> 3;
  int c = c0 + ch;

  float wg[49];
#pragma unroll
  for (int k2 = 0; k2 < 49; ++k2) wg[k2] = dww[c * 49 + k2];
  float bias = dwb[c];

  for (int q = tid; q < 1360; q += 256) {
    s16x8 z = {0, 0, 0, 0, 0, 0, 0, 0};
    *(s16x8*)(&plane[q * 8]) = z;
  }
  __syncthreads();
  for (int q = tid; q < 1568; q += 256) {
    int cc = q / 196, seg = q - cc * 196;
    int i = seg / 7, j4 = seg - i * 7;
    const float4 v = *(const float4*)(x + ((size_t)(b * 384 + c0 + cc)) * 784 +
                                      i * 28 + j4 * 4);
    s16x4 p;
    p[0] = (short)f2bf(v.x);
    p[1] = (short)f2bf(v.y);
    p[2] = (short)f2bf(v.z);
    p[3] = (short)f2bf(v.w);
    *(s16x4*)(&plane[cc * 1360 + (3 + i) * 40 + 4 + j4 * 4]) = p;
  }
  __syncthreads();

  if (row < 28) {
    size_t obase = ((size_t)(b * 784 + row * 28)) * 384 + c;
#pragma unroll
    for (int ck = 0; ck < 4; ++ck) {
      float acc[8];
#pragma unroll
      for (int o = 0; o < 8; ++o) acc[o] = bias;
#pragma unroll
      for (int di = 0; di < 7; ++di) {
        const u16* base2 = &plane[ch * 1360 + (row + di) * 40 + ck * 8];
        u32x4 ga = *(const u32x4*)(base2);
        u32x4 gb = *(const u32x4*)(base2 + 8);
        unsigned dw[8] = {ga[0], ga[1], ga[2], ga[3],
                          gb[0], gb[1], gb[2], gb[3]};
        float v[16];
#pragma unroll
        for (int tt = 0; tt < 16; ++tt) {
          unsigned d = dw[tt >> 1];
          v[tt] = (tt & 1) ? __builtin_bit_cast(float, d & 0xFFFF0000u)
                           : __builtin_bit_cast(float, d << 16);
        }
#pragma unroll
        for (int o = 0; o < 8; ++o)
#pragma unroll
          for (int dj = 0; dj < 7; ++dj)
            acc[o] += v[o + dj + 1] * wg[di * 7 + dj];
      }
      int lim = (ck == 3) ? 4 : 8;
#pragma unroll
      for (int o = 0; o < 8; ++o)
        if (o < lim) t[obase + (size_t)(ck * 8 + o) * 384] = f2bf(acc[o]);
    }
  }
}

// ---------------- K2: gather + LayerNorm -> A1 (fp8), A2 (bf16) ----------------
__global__ __launch_bounds__(256) void gatherln_kernel(
    const u16* __restrict__ t, const int* __restrict__ idx1,
    const int* __restrict__ idx2, const float* __restrict__ nw1,
    const float* __restrict__ nb1, const float* __restrict__ nw2,
    const float* __restrict__ nb2, u8* __restrict__ A1f,
    u16* __restrict__ A2) {
  int wid = threadIdx.x >> 6, lane = threadIdx.x & 63;
  int g = blockIdx.x * 4 + wid;
  bool is1 = g < 50176;
  int gg = is1 ? g : g - 50176;
  const int* idx = is1 ? idx1 : idx2;
  int b = gg / 392;
  int jj = gg - b * 392;
  int ntok = idx[b * 392 + jj];
  const u16* src = t + ((size_t)(b * 784 + ntok)) * 384 + lane * 6;
  float v[6];
  u16x2 u0 = *(const u16x2*)(src);
  u16x2 u1 = *(const u16x2*)(src + 2);
  u16x2 u2 = *(const u16x2*)(src + 4);
  v[0] = bf2f(u0[0]); v[1] = bf2f(u0[1]);
  v[2] = bf2f(u1[0]); v[3] = bf2f(u1[1]);
  v[4] = bf2f(u2[0]); v[5] = bf2f(u2[1]);
  float s = 0.f, q = 0.f;
#pragma unroll
  for (int e = 0; e < 6; ++e) { s += v[e]; q += v[e] * v[e]; }
#pragma unroll
  for (int off = 32; off >= 1; off >>= 1) {
    s += __shfl_xor(s, off);
    q += __shfl_xor(q, off);
  }
  float mu = s * (1.f / 384.f);
  float var = q * (1.f / 384.f) - mu * mu;
  float rs = rsqrtf(var + 1e-6f);
  const float* nw = is1 ? nw1 : nw2;
  const float* nb = is1 ? nb1 : nb2;
  int k0 = lane * 6;
  float o[6];
#pragma unroll
  for (int e = 0; e < 6; ++e)
    o[e] = (v[e] - mu) * rs * nw[k0 + e] + nb[k0 + e];
  if (is1) {
    u8* dst = A1f + (size_t)gg * 384 + lane * 6;
#pragma unroll
    for (int e = 0; e < 6; e += 2) *(u16*)(dst + e) = (u16)cvt2e4(o[e], o[e + 1]);
  } else {
    u16* dst = A2 + (size_t)gg * 384 + lane * 6;
#pragma unroll
    for (int e = 0; e < 6; ++e) dst[e] = f2bf(o[e]);
  }
}

// ---------------- K3+K4 FUSED (fp8): U[rm1] = (gelu(A1@W1+b1)@W2 + b2)*gamma ----
// BM=32, 256 thr (4 waves). fp8 e4m3 datapath (W pre-scaled x64).
// Per-block state halved vs R14 (accA[2][3], accB[2][6], LDS 24 KB) so
// 4 blocks/CU fit by LDS+VGPR -> ~16 waves/CU latency hiding (R14 had 8).
// Alds 12 KB (loaded once); Plds double-buffered 2x6 KB, one barrier/chunk.
__global__ __launch_bounds__(256, 2) void fused_mlp_kernel(
    const u8* __restrict__ A, const u8* __restrict__ w1p8,
    const u8* __restrict__ w2p8, const float* __restrict__ b1,
    const float* __restrict__ b2, const float* __restrict__ gamma,
    const int* __restrict__ rm, u16* __restrict__ U) {
  __shared__ __align__(16) u8 Alds[48 * 32 * 8];     // 12288 B
  __shared__ __align__(16) u8 Plds[2][24 * 32 * 8];  // 2 x 6144 B
  int tid = threadIdx.x;
  int wid = tid >> 6, lane = tid & 63;
  int kgl = lane >> 4, rl = lane & 15;
  int cl = lane & 15, rg = (lane >> 4) * 4;
  int m_base = blockIdx.x * 32;

  // stage A-tile (32 rows x 384 fp8 = 12KB): coalesced 16B loads, 2x b64 LDS
  // writes into octet layout [ko][row][8]
#pragma unroll
  for (int it = 0; it < 3; ++it) {
    int c16 = it * 256 + tid;      // 16B chunk id, 24 per row (768 total)
    int row = c16 / 24, cc = c16 - row * 24;
    u32x4 v = *(const u32x4*)(A + (size_t)(m_base + row) * 384 + cc * 16);
    u32x2 lo = {v[0], v[1]}, hi = {v[2], v[3]};
    *(u32x2*)&Alds[((2 * cc) * 32 + row) * 8] = lo;
    *(u32x2*)&Alds[((2 * cc + 1) * 32 + row) * 8] = hi;
  }

  const f32x4 vzero = {0.f, 0.f, 0.f, 0.f};
  f32x4 accB[2][6];
#pragma unroll
  for (int i = 0; i < 2; ++i)
#pragma unroll
    for (int j = 0; j < 6; ++j) accB[i][j] = vzero;

  __syncthreads();

#pragma unroll 1
  for (int c = 0; c < 8; ++c) {
    u8* Pl = Plds[c & 1];
    // ---- phase A: accA = A(32x384) @ W1[:, c*192 + wid*48 .. +48] ----
    f32x4 accA[2][3];
#pragma unroll
    for (int i = 0; i < 2; ++i)
#pragma unroll
      for (int j = 0; j < 3; ++j) accA[i][j] = vzero;
#pragma unroll
    for (int ks = 0; ks < 12; ++ks) {
      long af[2], bw[3];
#pragma unroll
      for (int i = 0; i < 2; ++i)
        af[i] = *(const long*)&Alds[((ks * 4 + kgl) * 32 + i * 16 + rl) * 8];
#pragma unroll
      for (int j = 0; j < 3; ++j) {
        int col = c * 192 + wid * 48 + j * 16 + rl;
        bw[j] = *(const long*)(w1p8 + ((size_t)(ks * 4 + kgl) * 1536 + col) * 8);
      }
      __builtin_amdgcn_s_setprio(1);
#pragma unroll
      for (int i = 0; i < 2; ++i)
#pragma unroll
        for (int j = 0; j < 3; ++j)
          accA[i][j] = mfma8(af[i], bw[j], accA[i][j]);
      __builtin_amdgcn_s_setprio(0);
    }
    // bias + sigmoid-gelu -> Pl fp8 (unscale W1's x64); pairs via cvt_pk
    float b1v[3];
#pragma unroll
    for (int j = 0; j < 3; ++j) b1v[j] = b1[c * 192 + wid * 48 + j * 16 + cl];
#pragma unroll
    for (int i = 0; i < 2; ++i)
#pragma unroll
      for (int j = 0; j < 3; ++j) {
        int col = wid * 48 + j * 16 + cl;
        float g2[4];
#pragma unroll
        for (int reg = 0; reg < 4; ++reg) {
          float v = accA[i][j][reg] * 0.015625f + b1v[j];
          g2[reg] = v / (1.f + __expf(-1.702f * v));
        }
        unsigned p01 = cvt2e4(g2[0], g2[1]);
        unsigned p23 = cvt2e4(g2[2], g2[3]);
        int base = ((col >> 3) * 32 + i * 16 + rg) * 8 + (col & 7);
        Pl[base] = (u8)p01;
        Pl[base + 8] = (u8)(p01 >> 8);
        Pl[base + 16] = (u8)p23;
        Pl[base + 24] = (u8)(p23 >> 8);
      }
    __syncthreads();
    // ---- phase B: accB += P(32x192) @ W2[c*192.., wid*96 .. +96] ----
#pragma unroll
    for (int ks = 0; ks < 6; ++ks) {
      long ap[2], bw2[6];
#pragma unroll
      for (int i = 0; i < 2; ++i)
        ap[i] = *(const long*)&Pl[((ks * 4 + kgl) * 32 + i * 16 + rl) * 8];
#pragma unroll
      for (int j = 0; j < 6; ++j) {
        int col = wid * 96 + j * 16 + rl;
        int ko2 = c * 24 + ks * 4 + kgl;
        bw2[j] = *(const long*)(w2p8 + ((size_t)ko2 * 384 + col) * 8);
      }
      __builtin_amdgcn_s_setprio(1);
#pragma unroll
      for (int i = 0; i < 2; ++i)
#pragma unroll
        for (int j = 0; j < 6; ++j)
          accB[i][j] = mfma8(ap[i], bw2[j], accB[i][j]);
      __builtin_amdgcn_s_setprio(0);
    }
    // no second barrier: next chunk writes the OTHER P buffer
  }

  // epilogue: U[rm[m]*384 + col] = bf16((accB/64 + b2[col]) * gamma[col])
#pragma unroll
  for (int i = 0; i < 2; ++i) {
#pragma unroll
    for (int reg = 0; reg < 4; ++reg) {
      int m = m_base + i * 16 + rg + reg;
      size_t rowoff = (size_t)rm[m] * 384;
#pragma unroll
      for (int j = 0; j < 6; ++j) {
        int col = wid * 96 + j * 16 + cl;
        float v = (accB[i][j][reg] * 0.015625f + b2[col]) * gamma[col];
        U[rowoff + col] = f2bf(v);
      }
    }
  }
}

// ---------------- K5: bf16 MFMA GEMM, 128x128 tile, 4 waves (R5 dbuf) ----
__global__ __launch_bounds__(256) void gemm_kernel(
    const u16* __restrict__ A, const u16* __restrict__ Wp,
    const float* __restrict__ bias, const float* __restrict__ scale,
    const int* __restrict__ rowmap, u16* __restrict__ out, int N, int K,
    int gx) {
  __shared__ __align__(16) u16 As[2][4096];
  __shared__ __align__(16) u16 Bs[2][4096];
  int tid = threadIdx.x;
  int wid = tid >> 6, lane = tid & 63;
  int wm = wid >> 1, wn = wid & 1;
  int nwg = gridDim.x;
  int bid = blockIdx.x;
  int wgid = (bid & 7) * (nwg >> 3) + (bid >> 3);
  int by = wgid / gx, bx = wgid - by * gx;
  int m_base = by * 128, n_base = bx * 128;
  const f32x4 vzero = {0.f, 0.f, 0.f, 0.f};
  f32x4 acc[4][4];
#pragma unroll
  for (int i = 0; i < 4; ++i)
#pragma unroll
    for (int j = 0; j < 4; ++j) acc[i][j] = vzero;
  int nk = K >> 5;

  auto stage = [&](int buf, int kt) {
#pragma unroll
    for (int it = 0; it < 2; ++it) {
      int p = wid * 128 + it * 64 + lane;
      int kg = p >> 7, row = p & 127;
      const u16* ga = A + (size_t)(m_base + row) * K + (kt << 5) + (kg << 3);
      gload_lds16(ga, &As[buf][(wid * 128 + it * 64) * 8]);
    }
#pragma unroll
    for (int it = 0; it < 2; ++it) {
      int p = wid * 128 + it * 64 + lane;
      int kg = p >> 7, col = p & 127;
      const u16* gb = Wp + ((size_t)((kt << 2) + kg) * N + n_base + col) * 8;
      gload_lds16(gb, &Bs[buf][(wid * 128 + it * 64) * 8]);
    }
  };

  stage(0, 0);
  __syncthreads();
  int cur = 0;
  for (int kt = 0; kt < nk; ++kt) {
    if (kt + 1 < nk) stage(cur ^ 1, kt + 1);
    int kg = lane >> 4, r = lane & 15;
    s16x8 af[4], bfr[4];
#pragma unroll
    for (int i = 0; i < 4; ++i)
      af[i] = *(const s16x8*)(&As[cur][(kg * 128 + wm * 64 + i * 16 + r) * 8]);
#pragma unroll
    for (int j = 0; j < 4; ++j)
      bfr[j] = *(const s16x8*)(&Bs[cur][(kg * 128 + wn * 64 + j * 16 + r) * 8]);
#pragma unroll
    for (int i = 0; i < 4; ++i)
#pragma unroll
      for (int j = 0; j < 4; ++j)
        acc[i][j] = mfma16x16x32(af[i], bfr[j], acc[i][j]);
    __syncthreads();
    cur ^= 1;
  }
  int cl = lane & 15;
  int rg = (lane >> 4) * 4;
#pragma unroll
  for (int i = 0; i < 4; ++i) {
#pragma unroll
    for (int reg = 0; reg < 4; ++reg) {
      int m = m_base + wm * 64 + i * 16 + rg + reg;
      size_t rowoff = (size_t)rowmap[m] * 384;
#pragma unroll
      for (int j = 0; j < 4; ++j) {
        int col = n_base + wn * 64 + j * 16 + cl;
        float v = acc[i][j][reg];
        v = (v + bias[col]) * scale[col];
        out[rowoff + col] = f2bf(v);
      }
    }
  }
}

// ---------------- K6: un-transpose (B,N,C)->(B,C,N) + residual add ----------------
// Vectorized: 32c x 128n tile; U reads s16x4 (8B/lane), x/out float4 IO.
__global__ __launch_bounds__(256) void unscatter_add_kernel(
    const u16* __restrict__ U, const float* __restrict__ x,
    float* __restrict__ out) {
  __shared__ float tile[32][129];
  int b = blockIdx.y;
  int ct = blockIdx.x % 12, nt = blockIdx.x / 12;
  int c0 = ct * 32, n0 = nt * 128;
  int tid = threadIdx.x;
#pragma unroll
  for (int it = 0; it < 4; ++it) {
    int q = tid + it * 256;
    int nl = q >> 3, cg = (q & 7) * 4;
    int n = n0 + nl;
    if (n < 784) {
      s16x4 v = *(const s16x4*)(U + ((size_t)(b * 784 + n)) * 384 + c0 + cg);
      tile[cg + 0][nl] = bf2f((u16)v[0]);
      tile[cg + 1][nl] = bf2f((u16)v[1]);
      tile[cg + 2][nl] = bf2f((u16)v[2]);
      tile[cg + 3][nl] = bf2f((u16)v[3]);
    }
  }
  __syncthreads();
#pragma unroll
  for (int it = 0; it < 4; ++it) {
    int q = tid + it * 256;
    int c = q >> 5, nf = (q & 31) * 4;
    int n = n0 + nf;
    if (n + 3 < 784) {
      size_t o = ((size_t)(b * 384 + c0 + c)) * 784 + n;
      float4 xv = *(const float4*)(x + o);
      float4 r;
      r.x = xv.x + tile[c][nf + 0];
      r.y = xv.y + tile[c][nf + 1];
      r.z = xv.z + tile[c][nf + 2];
      r.w = xv.w + tile[c][nf + 3];
      *(float4*)(out + o) = r;
    }
  }
}

extern "C" void kernel_launch(void* const* d_in, const int* in_sizes, int n_in,
                              void* d_out, int out_size, void* d_ws,
                              size_t ws_size, hipStream_t stream) {
  const float* x = (const float*)d_in[0];
  const int* idx1 = (const int*)d_in[1];
  const int* idx2 = (const int*)d_in[2];
  const float* dww = (const float*)d_in[3];
  const float* dwb = (const float*)d_in[4];
  const float* nw = (const float*)d_in[5];
  const float* nb = (const float*)d_in[6];
  const float* w1 = (const float*)d_in[7];
  const float* b1 = (const float*)d_in[8];
  const float* w2 = (const float*)d_in[9];
  const float* b2 = (const float*)d_in[10];
  const float* gamma = (const float*)d_in[11];
  const float* fnw = (const float*)d_in[12];
  const float* fnb = (const float*)d_in[13];
  const float* fpw = (const float*)d_in[14];
  const float* fpb = (const float*)d_in[15];
  const float* fpg = (const float*)d_in[16];

  char* ws = (char*)d_ws;
  u16* t = (u16*)(ws);                     //  77,070,336 B (100352x384 bf16)
  u8* A1f = (u8*)(ws + 77070336);          //  19,267,584 B (50176x384 fp8)
  u16* A2 = (u16*)(ws + 96337920);         //  38,535,168 B (50176x384 bf16)
  u16* U = (u16*)(ws + 134873088);         //  77,070,336 B (100352x384 bf16)
  u8* w1p8 = (u8*)(ws + 211943424);        //     589,824 B
  u8* w2p8 = (u8*)(ws + 212533248);        //     589,824 B
  u16* fpwp = (u16*)(ws + 213123072);      //     294,912 B
  int* rm1 = (int*)(ws + 213417984);       //     200,704 B
  int* rm2 = (int*)(ws + 213618688);       //     200,704 B
  (void)ws_size; (void)in_sizes; (void)n_in; (void)out_size;

  pack_kernel<<<1024, 256, 0, stream>>>(w1, w2, fpw, idx1, idx2, w1p8, w2p8,
                                        fpwp, rm1, rm2);
  dwconv_kernel<<<dim3(48, 128), 256, 0, stream>>>(x, dww, dwb, t);
  gatherln_kernel<<<25088, 256, 0, stream>>>(t, idx1, idx2, nw, nb, fnw, fnb,
                                             A1f, A2);
  fused_mlp_kernel<<<1568, 256, 0, stream>>>(A1f, w1p8, w2p8, b1, b2, gamma,
                                             rm1, U);
  gemm_kernel<<<1176, 256, 0, stream>>>(A2, fpwp, fpb, fpg, rm2, U, 384, 384,
                                        3);
  unscatter_add_kernel<<<dim3(84, 128), 256, 0, stream>>>(U, x,
                                                          (float*)d_out);
}

// Round 19
// 411.197 us; speedup vs baseline: 1.0926x; 1.0236x over previous
//
#include <hip/hip_runtime.h>
#include <hip/hip_fp8.h>
#include <math.h>

typedef unsigned short u16;
typedef unsigned char u8;
typedef short s16x8 __attribute__((ext_vector_type(8)));
typedef short s16x4 __attribute__((ext_vector_type(4)));
typedef unsigned int u32x4 __attribute__((ext_vector_type(4)));
typedef unsigned int u32x2 __attribute__((ext_vector_type(2)));
typedef __bf16 bf16x8 __attribute__((ext_vector_type(8)));
typedef float f32x4 __attribute__((ext_vector_type(4)));
typedef unsigned short u16x2 __attribute__((ext_vector_type(2)));

__device__ __forceinline__ float bf2f(u16 u) {
  unsigned x = ((unsigned)u) << 16;
  return __builtin_bit_cast(float, x);
}
__device__ __forceinline__ u16 f2bf(float f) {
  unsigned x = __builtin_bit_cast(unsigned, f);
  unsigned r = (x + 0x7FFFu + ((x >> 16) & 1u)) >> 16;
  return (u16)r;
}
__device__ __forceinline__ u8 f2e4(float f) {
  __hip_fp8_e4m3 q(f);
  return (u8)q.__x;
}
// packed f32x2 -> 2 fp8 bytes (hardware v_cvt_pk_fp8_f32 when available)
__device__ __forceinline__ unsigned cvt2e4(float a, float b) {
#if __has_builtin(__builtin_amdgcn_cvt_pk_fp8_f32)
  return (unsigned)__builtin_amdgcn_cvt_pk_fp8_f32(a, b, 0, false) & 0xFFFFu;
#else
  return (unsigned)f2e4(a) | ((unsigned)f2e4(b) << 8);
#endif
}

// ---- bf16 MFMA wrapper (signature-robust) ----
template <typename T>
__device__ __forceinline__ auto mfma_try(T a, T b, f32x4 c, int)
    -> decltype(__builtin_amdgcn_mfma_f32_16x16x32_bf16(a, b, c, 0, 0, 0)) {
  return __builtin_amdgcn_mfma_f32_16x16x32_bf16(a, b, c, 0, 0, 0);
}
template <typename T>
__device__ __forceinline__ f32x4 mfma_try(T a, T b, f32x4 c, long) {
  return __builtin_amdgcn_mfma_f32_16x16x32_bf16(
      __builtin_bit_cast(bf16x8, a), __builtin_bit_cast(bf16x8, b), c, 0, 0, 0);
}
__device__ __forceinline__ f32x4 mfma16x16x32(s16x8 a, s16x8 b, f32x4 c) {
  return mfma_try(a, b, c, 0);
}

// ---- fp8 MFMA: builtin operand type is 'long' (i64) on gfx950 ----
__device__ __forceinline__ f32x4 mfma8(long a, long b, f32x4 c) {
  return __builtin_amdgcn_mfma_f32_16x16x32_fp8_fp8(a, b, c, 0, 0, 0);
}

// ---- async global->LDS, 16B per lane ----
__device__ __forceinline__ void gload_lds16(const u16* g, u16* l) {
  __builtin_amdgcn_global_load_lds(
      (__attribute__((address_space(1))) void*)(u16*)g,
      (__attribute__((address_space(3))) void*)l, 16, 0, 0);
}

// ---------------- K0: pack weights (W1,W2 -> fp8x64 octets; fp_w -> bf16), rowmaps ----
__global__ __launch_bounds__(256) void pack_kernel(
    const float* __restrict__ w1, const float* __restrict__ w2,
    const float* __restrict__ fpw, const int* __restrict__ idx1,
    const int* __restrict__ idx2, u8* __restrict__ w1p8, u8* __restrict__ w2p8,
    u16* __restrict__ fpwp, int* __restrict__ rm1, int* __restrict__ rm2) {
  const int T1 = 589824;           // w1 (384x1536)
  const int T2 = T1 + 589824;      // w2 (1536x384)
  const int T3 = T2 + 147456;      // fp_w (384x384)
  const int T4 = T3 + 50176;       // rowmap1
  const int T5 = T4 + 50176;       // rowmap2
  int stride = gridDim.x * 256;
  for (int i = blockIdx.x * 256 + threadIdx.x; i < T5; i += stride) {
    if (i < T1) {
      int k = i / 1536, n = i - k * 1536;
      w1p8[((size_t)(k >> 3) * 1536 + n) * 8 + (k & 7)] = f2e4(w1[i] * 64.f);
    } else if (i < T2) {
      int t = i - T1;
      int k = t / 384, n = t - k * 384;
      w2p8[((size_t)(k >> 3) * 384 + n) * 8 + (k & 7)] = f2e4(w2[t] * 64.f);
    } else if (i < T3) {
      int t = i - T2;
      int k = t / 384, n = t - k * 384;
      fpwp[((size_t)(k >> 3) * 384 + n) * 8 + (k & 7)] = f2bf(fpw[t]);
    } else if (i < T4) {
      int g = i - T3;
      rm1[g] = (g / 392) * 784 + idx1[g];
    } else {
      int g = i - T4;
      rm2[g] = (g / 392) * 784 + idx2[g];
    }
  }
}

// ---------------- K1: depthwise 7x7 conv + bias -> t (B,N,C) bf16 ----------------
__global__ __launch_bounds__(256) void dwconv_kernel(
    const float* __restrict__ x, const float* __restrict__ dww,
    const float* __restrict__ dwb, u16* __restrict__ t) {
  __shared__ __align__(16) u16 plane[8 * 34 * 40];  // 21760 B
  int tid = threadIdx.x;
  int b = blockIdx.y, c0 = blockIdx.x * 8;
  int ch = tid & 7, row = tid >> 3;
  int c = c0 + ch;

  float wg[49];
#pragma unroll
  for (int k2 = 0; k2 < 49; ++k2) wg[k2] = dww[c * 49 + k2];
  float bias = dwb[c];

  for (int q = tid; q < 1360; q += 256) {
    s16x8 z = {0, 0, 0, 0, 0, 0, 0, 0};
    *(s16x8*)(&plane[q * 8]) = z;
  }
  __syncthreads();
  for (int q = tid; q < 1568; q += 256) {
    int cc = q / 196, seg = q - cc * 196;
    int i = seg / 7, j4 = seg - i * 7;
    const float4 v = *(const float4*)(x + ((size_t)(b * 384 + c0 + cc)) * 784 +
                                      i * 28 + j4 * 4);
    s16x4 p;
    p[0] = (short)f2bf(v.x);
    p[1] = (short)f2bf(v.y);
    p[2] = (short)f2bf(v.z);
    p[3] = (short)f2bf(v.w);
    *(s16x4*)(&plane[cc * 1360 + (3 + i) * 40 + 4 + j4 * 4]) = p;
  }
  __syncthreads();

  if (row < 28) {
    size_t obase = ((size_t)(b * 784 + row * 28)) * 384 + c;
#pragma unroll
    for (int ck = 0; ck < 4; ++ck) {
      float acc[8];
#pragma unroll
      for (int o = 0; o < 8; ++o) acc[o] = bias;
#pragma unroll
      for (int di = 0; di < 7; ++di) {
        const u16* base2 = &plane[ch * 1360 + (row + di) * 40 + ck * 8];
        u32x4 ga = *(const u32x4*)(base2);
        u32x4 gb = *(const u32x4*)(base2 + 8);
        unsigned dw[8] = {ga[0], ga[1], ga[2], ga[3],
                          gb[0], gb[1], gb[2], gb[3]};
        float v[16];
#pragma unroll
        for (int tt = 0; tt < 16; ++tt) {
          unsigned d = dw[tt >> 1];
          v[tt] = (tt & 1) ? __builtin_bit_cast(float, d & 0xFFFF0000u)
                           : __builtin_bit_cast(float, d << 16);
        }
#pragma unroll
        for (int o = 0; o < 8; ++o)
#pragma unroll
          for (int dj = 0; dj < 7; ++dj)
            acc[o] += v[o + dj + 1] * wg[di * 7 + dj];
      }
      int lim = (ck == 3) ? 4 : 8;
#pragma unroll
      for (int o = 0; o < 8; ++o)
        if (o < lim) t[obase + (size_t)(ck * 8 + o) * 384] = f2bf(acc[o]);
    }
  }
}

// ---------------- K2: gather + LayerNorm -> A1 (fp8), A2 (bf16) ----------------
__global__ __launch_bounds__(256) void gatherln_kernel(
    const u16* __restrict__ t, const int* __restrict__ idx1,
    const int* __restrict__ idx2, const float* __restrict__ nw1,
    const float* __restrict__ nb1, const float* __restrict__ nw2,
    const float* __restrict__ nb2, u8* __restrict__ A1f,
    u16* __restrict__ A2) {
  int wid = threadIdx.x >> 6, lane = threadIdx.x & 63;
  int g = blockIdx.x * 4 + wid;
  bool is1 = g < 50176;
  int gg = is1 ? g : g - 50176;
  const int* idx = is1 ? idx1 : idx2;
  int b = gg / 392;
  int jj = gg - b * 392;
  int ntok = idx[b * 392 + jj];
  const u16* src = t + ((size_t)(b * 784 + ntok)) * 384 + lane * 6;
  float v[6];
  u16x2 u0 = *(const u16x2*)(src);
  u16x2 u1 = *(const u16x2*)(src + 2);
  u16x2 u2 = *(const u16x2*)(src + 4);
  v[0] = bf2f(u0[0]); v[1] = bf2f(u0[1]);
  v[2] = bf2f(u1[0]); v[3] = bf2f(u1[1]);
  v[4] = bf2f(u2[0]); v[5] = bf2f(u2[1]);
  float s = 0.f, q = 0.f;
#pragma unroll
  for (int e = 0; e < 6; ++e) { s += v[e]; q += v[e] * v[e]; }
#pragma unroll
  for (int off = 32; off >= 1; off >>= 1) {
    s += __shfl_xor(s, off);
    q += __shfl_xor(q, off);
  }
  float mu = s * (1.f / 384.f);
  float var = q * (1.f / 384.f) - mu * mu;
  float rs = rsqrtf(var + 1e-6f);
  const float* nw = is1 ? nw1 : nw2;
  const float* nb = is1 ? nb1 : nb2;
  int k0 = lane * 6;
  float o[6];
#pragma unroll
  for (int e = 0; e < 6; ++e)
    o[e] = (v[e] - mu) * rs * nw[k0 + e] + nb[k0 + e];
  if (is1) {
    u8* dst = A1f + (size_t)gg * 384 + lane * 6;
#pragma unroll
    for (int e = 0; e < 6; e += 2) *(u16*)(dst + e) = (u16)cvt2e4(o[e], o[e + 1]);
  } else {
    unsigned* dst = (unsigned*)(A2 + (size_t)gg * 384 + lane * 6);
#pragma unroll
    for (int e = 0; e < 3; ++e)
      dst[e] = (unsigned)f2bf(o[2 * e]) | ((unsigned)f2bf(o[2 * e + 1]) << 16);
  }
}

// ---------------- K3+K4 FUSED (fp8): U[rm1] = (gelu(A1@W1+b1)@W2 + b2)*gamma ----
// BM=32, 256 thr (4 waves). fp8 e4m3 datapath (W pre-scaled x64).
// Hard-sigmoid gelu (no transcendentals; error gamma-damped to ~1e-8).
// launch_bounds(256,4): total regs (acc 72 + ~52 VGPR) fit the 128 cliff ->
// 4 waves/SIMD (R18 was 132 regs -> 3 waves/SIMD at 34% occ).
// Alds 12 KB (loaded once); Plds double-buffered 2x6 KB, one barrier/chunk.
__global__ __launch_bounds__(256, 4) void fused_mlp_kernel(
    const u8* __restrict__ A, const u8* __restrict__ w1p8,
    const u8* __restrict__ w2p8, const float* __restrict__ b1,
    const float* __restrict__ b2, const float* __restrict__ gamma,
    const int* __restrict__ rm, u16* __restrict__ U) {
  __shared__ __align__(16) u8 Alds[48 * 32 * 8];     // 12288 B
  __shared__ __align__(16) u8 Plds[2][24 * 32 * 8];  // 2 x 6144 B
  int tid = threadIdx.x;
  int wid = tid >> 6, lane = tid & 63;
  int kgl = lane >> 4, rl = lane & 15;
  int cl = lane & 15, rg = (lane >> 4) * 4;
  int m_base = blockIdx.x * 32;

  // stage A-tile (32 rows x 384 fp8 = 12KB): coalesced 16B loads, 2x b64 LDS
  // writes into octet layout [ko][row][8]
#pragma unroll
  for (int it = 0; it < 3; ++it) {
    int c16 = it * 256 + tid;      // 16B chunk id, 24 per row (768 total)
    int row = c16 / 24, cc = c16 - row * 24;
    u32x4 v = *(const u32x4*)(A + (size_t)(m_base + row) * 384 + cc * 16);
    u32x2 lo = {v[0], v[1]}, hi = {v[2], v[3]};
    *(u32x2*)&Alds[((2 * cc) * 32 + row) * 8] = lo;
    *(u32x2*)&Alds[((2 * cc + 1) * 32 + row) * 8] = hi;
  }

  const f32x4 vzero = {0.f, 0.f, 0.f, 0.f};
  f32x4 accB[2][6];
#pragma unroll
  for (int i = 0; i < 2; ++i)
#pragma unroll
    for (int j = 0; j < 6; ++j) accB[i][j] = vzero;

  __syncthreads();

#pragma unroll 1
  for (int c = 0; c < 8; ++c) {
    u8* Pl = Plds[c & 1];
    // ---- phase A: accA = A(32x384) @ W1[:, c*192 + wid*48 .. +48] ----
    f32x4 accA[2][3];
#pragma unroll
    for (int i = 0; i < 2; ++i)
#pragma unroll
      for (int j = 0; j < 3; ++j) accA[i][j] = vzero;
#pragma unroll
    for (int ks = 0; ks < 12; ++ks) {
      long af[2], bw[3];
#pragma unroll
      for (int i = 0; i < 2; ++i)
        af[i] = *(const long*)&Alds[((ks * 4 + kgl) * 32 + i * 16 + rl) * 8];
#pragma unroll
      for (int j = 0; j < 3; ++j) {
        int col = c * 192 + wid * 48 + j * 16 + rl;
        bw[j] = *(const long*)(w1p8 + ((size_t)(ks * 4 + kgl) * 1536 + col) * 8);
      }
      __builtin_amdgcn_s_setprio(1);
#pragma unroll
      for (int i = 0; i < 2; ++i)
#pragma unroll
        for (int j = 0; j < 3; ++j)
          accA[i][j] = mfma8(af[i], bw[j], accA[i][j]);
      __builtin_amdgcn_s_setprio(0);
    }
    // bias + hard-sigmoid gelu -> Pl fp8 (unscale W1's x64)
    float b1v[3];
#pragma unroll
    for (int j = 0; j < 3; ++j) b1v[j] = b1[c * 192 + wid * 48 + j * 16 + cl];
#pragma unroll
    for (int i = 0; i < 2; ++i)
#pragma unroll
      for (int j = 0; j < 3; ++j) {
        int col = wid * 48 + j * 16 + cl;
        float g2[4];
#pragma unroll
        for (int reg = 0; reg < 4; ++reg) {
          float v = accA[i][j][reg] * 0.015625f + b1v[j];
          g2[reg] = v * fminf(fmaxf(0.4255f * v + 0.5f, 0.f), 1.f);
        }
        unsigned p01 = cvt2e4(g2[0], g2[1]);
        unsigned p23 = cvt2e4(g2[2], g2[3]);
        int base = ((col >> 3) * 32 + i * 16 + rg) * 8 + (col & 7);
        Pl[base] = (u8)p01;
        Pl[base + 8] = (u8)(p01 >> 8);
        Pl[base + 16] = (u8)p23;
        Pl[base + 24] = (u8)(p23 >> 8);
      }
    __syncthreads();
    // ---- phase B: accB += P(32x192) @ W2[c*192.., wid*96 .. +96] ----
#pragma unroll
    for (int ks = 0; ks < 6; ++ks) {
      long ap[2], bw2[6];
#pragma unroll
      for (int i = 0; i < 2; ++i)
        ap[i] = *(const long*)&Pl[((ks * 4 + kgl) * 32 + i * 16 + rl) * 8];
#pragma unroll
      for (int j = 0; j < 6; ++j) {
        int col = wid * 96 + j * 16 + rl;
        int ko2 = c * 24 + ks * 4 + kgl;
        bw2[j] = *(const long*)(w2p8 + ((size_t)ko2 * 384 + col) * 8);
      }
      __builtin_amdgcn_s_setprio(1);
#pragma unroll
      for (int i = 0; i < 2; ++i)
#pragma unroll
        for (int j = 0; j < 6; ++j)
          accB[i][j] = mfma8(ap[i], bw2[j], accB[i][j]);
      __builtin_amdgcn_s_setprio(0);
    }
    // no second barrier: next chunk writes the OTHER P buffer
  }

  // epilogue: U[rm[m]*384 + col] = bf16((accB/64 + b2[col]) * gamma[col])
#pragma unroll
  for (int i = 0; i < 2; ++i) {
#pragma unroll
    for (int reg = 0; reg < 4; ++reg) {
      int m = m_base + i * 16 + rg + reg;
      size_t rowoff = (size_t)rm[m] * 384;
#pragma unroll
      for (int j = 0; j < 6; ++j) {
        int col = wid * 96 + j * 16 + cl;
        float v = (accB[i][j][reg] * 0.015625f + b2[col]) * gamma[col];
        U[rowoff + col] = f2bf(v);
      }
    }
  }
}

// ---------------- K5: bf16 MFMA GEMM, 128x128 tile, 4 waves (R5 dbuf) ----
__global__ __launch_bounds__(256) void gemm_kernel(
    const u16* __restrict__ A, const u16* __restrict__ Wp,
    const float* __restrict__ bias, const float* __restrict__ scale,
    const int* __restrict__ rowmap, u16* __restrict__ out, int N, int K,
    int gx) {
  __shared__ __align__(16) u16 As[2][4096];
  __shared__ __align__(16) u16 Bs[2][4096];
  int tid = threadIdx.x;
  int wid = tid >> 6, lane = tid & 63;
  int wm = wid >> 1, wn = wid & 1;
  int nwg = gridDim.x;
  int bid = blockIdx.x;
  int wgid = (bid & 7) * (nwg >> 3) + (bid >> 3);
  int by = wgid / gx, bx = wgid - by * gx;
  int m_base = by * 128, n_base = bx * 128;
  const f32x4 vzero = {0.f, 0.f, 0.f, 0.f};
  f32x4 acc[4][4];
#pragma unroll
  for (int i = 0; i < 4; ++i)
#pragma unroll
    for (int j = 0; j < 4; ++j) acc[i][j] = vzero;
  int nk = K >> 5;

  auto stage = [&](int buf, int kt) {
#pragma unroll
    for (int it = 0; it < 2; ++it) {
      int p = wid * 128 + it * 64 + lane;
      int kg = p >> 7, row = p & 127;
      const u16* ga = A + (size_t)(m_base + row) * K + (kt << 5) + (kg << 3);
      gload_lds16(ga, &As[buf][(wid * 128 + it * 64) * 8]);
    }
#pragma unroll
    for (int it = 0; it < 2; ++it) {
      int p = wid * 128 + it * 64 + lane;
      int kg = p >> 7, col = p & 127;
      const u16* gb = Wp + ((size_t)((kt << 2) + kg) * N + n_base + col) * 8;
      gload_lds16(gb, &Bs[buf][(wid * 128 + it * 64) * 8]);
    }
  };

  stage(0, 0);
  __syncthreads();
  int cur = 0;
  for (int kt = 0; kt < nk; ++kt) {
    if (kt + 1 < nk) stage(cur ^ 1, kt + 1);
    int kg = lane >> 4, r = lane & 15;
    s16x8 af[4], bfr[4];
#pragma unroll
    for (int i = 0; i < 4; ++i)
      af[i] = *(const s16x8*)(&As[cur][(kg * 128 + wm * 64 + i * 16 + r) * 8]);
#pragma unroll
    for (int j = 0; j < 4; ++j)
      bfr[j] = *(const s16x8*)(&Bs[cur][(kg * 128 + wn * 64 + j * 16 + r) * 8]);
#pragma unroll
    for (int i = 0; i < 4; ++i)
#pragma unroll
      for (int j = 0; j < 4; ++j)
        acc[i][j] = mfma16x16x32(af[i], bfr[j], acc[i][j]);
    __syncthreads();
    cur ^= 1;
  }
  int cl = lane & 15;
  int rg = (lane >> 4) * 4;
#pragma unroll
  for (int i = 0; i < 4; ++i) {
#pragma unroll
    for (int reg = 0; reg < 4; ++reg) {
      int m = m_base + wm * 64 + i * 16 + rg + reg;
      size_t rowoff = (size_t)rowmap[m] * 384;
#pragma unroll
      for (int j = 0; j < 4; ++j) {
        int col = n_base + wn * 64 + j * 16 + cl;
        float v = acc[i][j][reg];
        v = (v + bias[col]) * scale[col];
        out[rowoff + col] = f2bf(v);
      }
    }
  }
}

// ---------------- K6: un-transpose (B,N,C)->(B,C,N) + residual add ----------------
// Vectorized: 32c x 128n tile; U reads s16x4 (8B/lane), x/out float4 IO.
__global__ __launch_bounds__(256) void unscatter_add_kernel(
    const u16* __restrict__ U, const float* __restrict__ x,
    float* __restrict__ out) {
  __shared__ float tile[32][129];
  int b = blockIdx.y;
  int ct = blockIdx.x % 12, nt = blockIdx.x / 12;
  int c0 = ct * 32, n0 = nt * 128;
  int tid = threadIdx.x;
#pragma unroll
  for (int it = 0; it < 4; ++it) {
    int q = tid + it * 256;
    int nl = q >> 3, cg = (q & 7) * 4;
    int n = n0 + nl;
    if (n < 784) {
      s16x4 v = *(const s16x4*)(U + ((size_t)(b * 784 + n)) * 384 + c0 + cg);
      tile[cg + 0][nl] = bf2f((u16)v[0]);
      tile[cg + 1][nl] = bf2f((u16)v[1]);
      tile[cg + 2][nl] = bf2f((u16)v[2]);
      tile[cg + 3][nl] = bf2f((u16)v[3]);
    }
  }
  __syncthreads();
#pragma unroll
  for (int it = 0; it < 4; ++it) {
    int q = tid + it * 256;
    int c = q >> 5, nf = (q & 31) * 4;
    int n = n0 + nf;
    if (n + 3 < 784) {
      size_t o = ((size_t)(b * 384 + c0 + c)) * 784 + n;
      float4 xv = *(const float4*)(x + o);
      float4 r;
      r.x = xv.x + tile[c][nf + 0];
      r.y = xv.y + tile[c][nf + 1];
      r.z = xv.z + tile[c][nf + 2];
      r.w = xv.w + tile[c][nf + 3];
      *(float4*)(out + o) = r;
    }
  }
}

extern "C" void kernel_launch(void* const* d_in, const int* in_sizes, int n_in,
                              void* d_out, int out_size, void* d_ws,
                              size_t ws_size, hipStream_t stream) {
  const float* x = (const float*)d_in[0];
  const int* idx1 = (const int*)d_in[1];
  const int* idx2 = (const int*)d_in[2];
  const float* dww = (const float*)d_in[3];
  const float* dwb = (const float*)d_in[4];
  const float* nw = (const float*)d_in[5];
  const float* nb = (const float*)d_in[6];
  const float* w1 = (const float*)d_in[7];
  const float* b1 = (const float*)d_in[8];
  const float* w2 = (const float*)d_in[9];
  const float* b2 = (const float*)d_in[10];
  const float* gamma = (const float*)d_in[11];
  const float* fnw = (const float*)d_in[12];
  const float* fnb = (const float*)d_in[13];
  const float* fpw = (const float*)d_in[14];
  const float* fpb = (const float*)d_in[15];
  const float* fpg = (const float*)d_in[16];

  char* ws = (char*)d_ws;
  u16* t = (u16*)(ws);                     //  77,070,336 B (100352x384 bf16)
  u8* A1f = (u8*)(ws + 77070336);          //  19,267,584 B (50176x384 fp8)
  u16* A2 = (u16*)(ws + 96337920);         //  38,535,168 B (50176x384 bf16)
  u16* U = (u16*)(ws + 134873088);         //  77,070,336 B (100352x384 bf16)
  u8* w1p8 = (u8*)(ws + 211943424);        //     589,824 B
  u8* w2p8 = (u8*)(ws + 212533248);        //     589,824 B
  u16* fpwp = (u16*)(ws + 213123072);      //     294,912 B
  int* rm1 = (int*)(ws + 213417984);       //     200,704 B
  int* rm2 = (int*)(ws + 213618688);       //     200,704 B
  (void)ws_size; (void)in_sizes; (void)n_in; (void)out_size;

  pack_kernel<<<1024, 256, 0, stream>>>(w1, w2, fpw, idx1, idx2, w1p8, w2p8,
                                        fpwp, rm1, rm2);
  dwconv_kernel<<<dim3(48, 128), 256, 0, stream>>>(x, dww, dwb, t);
  gatherln_kernel<<<25088, 256, 0, stream>>>(t, idx1, idx2, nw, nb, fnw, fnb,
                                             A1f, A2);
  fused_mlp_kernel<<<1568, 256, 0, stream>>>(A1f, w1p8, w2p8, b1, b2, gamma,
                                             rm1, U);
  gemm_kernel<<<1176, 256, 0, stream>>>(A2, fpwp, fpb, fpg, rm2, U, 384, 384,
                                        3);
  unscatter_add_kernel<<<dim3(84, 128), 256, 0, stream>>>(U, x,
                                                          (float*)d_out);
}